// Round 9
// baseline (395.005 us; speedup 1.0000x reference)
//
#include <hip/hip_runtime.h>
#include <cmath>

// B=4, S=4096, D_IN=1024, D_K=D_V=64
constexpr int B_  = 4;
constexpr int S_  = 4096;
constexpr int DIN = 1024;
constexpr int DH  = 64;

typedef short bf16x8 __attribute__((ext_vector_type(8)));
typedef float f32x4  __attribute__((ext_vector_type(4)));

#define GPTR(p) (const __attribute__((address_space(1))) unsigned int*)(p)
#define LPTR(p) (__attribute__((address_space(3))) unsigned int*)(p)

// fp32 -> bf16 RNE, raw bits
__device__ __forceinline__ ushort f2bf(float x) {
    unsigned int u = __float_as_uint(x);
    return (ushort)((u + 0x7FFFu + ((u >> 16) & 1u)) >> 16);
}

__device__ __forceinline__ bf16x8 cvt8(f32x4 a, f32x4 b) {
    union { bf16x8 v; ushort u[8]; } r;
    r.u[0] = f2bf(a[0]); r.u[1] = f2bf(a[1]); r.u[2] = f2bf(a[2]); r.u[3] = f2bf(a[3]);
    r.u[4] = f2bf(b[0]); r.u[5] = f2bf(b[1]); r.u[6] = f2bf(b[2]); r.u[7] = f2bf(b[3]);
    return r.v;
}

// softmax scale 1/8 with log2(e) folded in (softmax via exp2)
#define QSCALE 0.18033688011112042f

// ---------------------------------------------------------------------------
// setup_w: W[1024][64] fp32 -> FRAGMENT-ORDERED bf16 image (unchanged).
// Also zeroes the attn combine counters each iteration (runs before attn on
// the same stream -> ordering guaranteed; makes graph replay self-consistent).
// ---------------------------------------------------------------------------
__global__ __launch_bounds__(256) void setup_w(
    const float* __restrict__ Wq, const float* __restrict__ Wk,
    const float* __restrict__ Wv, ushort* __restrict__ Wt_g, int* __restrict__ cnt)
{
    const int y = blockIdx.y;
    if (y == 0 && blockIdx.x == 0 && threadIdx.x < 128) cnt[threadIdx.x] = 0;
    const float* W = (y == 0) ? Wq : (y == 1) ? Wk : Wv;
    const int g    = blockIdx.x * 256 + threadIdx.x;
    const int lane = g & 63;
    const int nt   = (g >> 6) & 3;
    const int ks   = (g >> 8) & 1;
    const int it   = g >> 9;
    const int m    = lane & 15;
    const int quad = lane >> 4;
    const int n    = nt * 16 + m;
    const int k0   = it * 64 + (ks * 4 + quad) * 8;
    union { uint4 q; ushort u[8]; } r;
    #pragma unroll
    for (int i = 0; i < 8; ++i) r.u[i] = f2bf(W[(size_t)(k0 + i) * DH + n]);
    *(uint4*)(Wt_g + ((size_t)y << 16) + (size_t)g * 8) = r.q;
}

// ---------------------------------------------------------------------------
// Projection v5 (FROZEN at its ~74-82us floor — six schedules r0-r5 all land
// there regardless of structure. Input-read service-rate cap. Do not touch.)
// ---------------------------------------------------------------------------
__global__ __launch_bounds__(256, 4) void proj_kernel(
    const float* __restrict__ Xq, const float* __restrict__ Xk, const float* __restrict__ Xv,
    const float* __restrict__ bq, const float* __restrict__ bk, const float* __restrict__ bv,
    const ushort* __restrict__ Wt_g,
    ushort* __restrict__ Qb, ushort* __restrict__ Kb, ushort* __restrict__ Vt)
{
    __shared__ __align__(16) ushort xlds[16384];   // 32KB

    const int y = blockIdx.y;
    const float *X, *bias;
    if (y == 0)      { X = Xq; bias = bq; }
    else if (y == 1) { X = Xk; bias = bk; }
    else             { X = Xv; bias = bv; }

    const int tid  = threadIdx.x;
    const int w    = tid >> 6;
    const int lane = tid & 63;
    const int m    = lane & 15;
    const int quad = lane >> 4;
    const int row0 = blockIdx.x * 16;

    {
        f32x4 va[8], vb[8];
        #pragma unroll
        for (int r = 0; r < 4; ++r) {
            const float* src = X + (size_t)(row0 + w * 4 + r) * DIN + lane * 8;
            #pragma unroll
            for (int sg = 0; sg < 2; ++sg) {
                va[r * 2 + sg] = *(const f32x4*)(src + sg * 512);
                vb[r * 2 + sg] = *(const f32x4*)(src + sg * 512 + 4);
            }
        }
        __builtin_amdgcn_sched_barrier(0);
        #pragma unroll
        for (int r = 0; r < 4; ++r) {
            const int row = w * 4 + r;
            #pragma unroll
            for (int sg = 0; sg < 2; ++sg) {
                const int wi = sg * 8 + (lane >> 3);
                const int fx = (lane & 7) ^ (row & 7);
                *(bf16x8*)&xlds[((wi * 16 + row) * 8 + fx) * 8] =
                    cvt8(va[r * 2 + sg], vb[r * 2 + sg]);
            }
        }
    }
    __syncthreads();

    const float bias_v = bias[w * 16 + m];
    const ushort* wbase = Wt_g + ((size_t)y << 16) + (size_t)(w * 64 + lane) * 8;

    f32x4 acc = {};
    bf16x8 wf0 = *(const bf16x8*)(wbase);
    bf16x8 wf1 = *(const bf16x8*)(wbase + 2048);
    #pragma unroll
    for (int wi = 0; wi < 16; ++wi) {
        bf16x8 nf0 = wf0, nf1 = wf1;
        if (wi < 15) {
            nf0 = *(const bf16x8*)(wbase + (size_t)(wi + 1) * 4096);
            nf1 = *(const bf16x8*)(wbase + (size_t)(wi + 1) * 4096 + 2048);
        }
        const bf16x8 a0 = *(const bf16x8*)&xlds[((wi * 16 + m) * 8 + ( quad      ^ (m & 7))) * 8];
        const bf16x8 a1 = *(const bf16x8*)&xlds[((wi * 16 + m) * 8 + ((4 + quad) ^ (m & 7))) * 8];
        acc = __builtin_amdgcn_mfma_f32_16x16x32_bf16(a0, wf0, acc, 0, 0, 0);
        acc = __builtin_amdgcn_mfma_f32_16x16x32_bf16(a1, wf1, acc, 0, 0, 0);
        wf0 = nf0; wf1 = nf1;
    }

    if (y < 2) {
        ushort* Out = (y == 0) ? Qb : Kb;
        const float sc = (y == 0) ? QSCALE : 1.0f;
        #pragma unroll
        for (int j = 0; j < 4; ++j) {
            const int row = row0 + quad * 4 + j;
            Out[(size_t)row * DH + w * 16 + m] = f2bf((acc[j] + bias_v) * sc);
        }
    } else {
        __syncthreads();
        ushort (*Vx)[32] = (ushort(*)[32])xlds;
        #pragma unroll
        for (int j = 0; j < 4; ++j)
            Vx[w * 16 + m][quad * 4 + j] = f2bf(acc[j] + bias_v);
        __syncthreads();
        const int batch = row0 >> 12;
        const int s0    = row0 & 4095;
        if (tid < 128) {
            const int d = tid >> 1, h = tid & 1;
            const uint4 v = *(const uint4*)&Vx[d][h * 8];
            *(uint4*)(Vt + ((size_t)batch * 64 + d) * S_ + s0 + h * 8) = v;
        }
    }
}

// ---------------------------------------------------------------------------
// Flash attention v5 = r8's v4 (BQ=128, XCD-pinned chunks, counted-vmcnt
// dbuf) + INLINE COMBINE via last-block-done: the 4 jc-partial blocks of each
// (b,qt) region count in on an atomic; the 4th arrival re-fences, sums the
// fp32 partials IN THE SAME ORDER as the old reduce kernel (bitwise-identical
// output), divides by L, writes final out, and resets the counter. r7's
// fusion failed because it halved parallelism; this one keeps the grid
// identical and only adds a ~3us tail to 128 of 512 blocks. Eliminates the
// reduce dispatch + its launch gap. Guideline-16: device-scope atomicAdd +
// __threadfence on both sides of the handoff.
// ---------------------------------------------------------------------------
__global__ __launch_bounds__(512, 4) void attn_kernel(
    const ushort* __restrict__ Qb, const ushort* __restrict__ Kb,
    const ushort* __restrict__ Vt, float* __restrict__ Opart,
    float* __restrict__ Lpart, int* __restrict__ cnt, float* __restrict__ out)
{
    __shared__ ushort Ks[2][4096];   // [buf][j][d], chunk-XOR swizzled (8KB)
    __shared__ ushort Vs[2][4096];   // [buf][d][j], chunk-XOR swizzled (8KB)
    __shared__ ushort Pt[128 * 72];  // per-wave stripes (8 waves), padded
    __shared__ int sOld;

    const int tid  = threadIdx.x;
    const int w    = tid >> 6;          // 0..7: q-rows [w*16, w*16+16)
    const int lane = tid & 63;
    const int m    = lane & 15;
    const int quad = lane >> 4;

    // XCD-locality remap: chunk c=(b,jc) pinned to XCD u&7 (2 chunks/XCD)
    const int u  = blockIdx.x;          // 0..511
    const int c  = (u & 7) * 2 + ((u >> 3) >> 5);
    const int qt = (u >> 3) & 31;
    const int b  = c >> 2, jc = c & 3;
    const int q0 = qt * 128;

    bf16x8 qf[2];
    #pragma unroll
    for (int ks = 0; ks < 2; ++ks)
        qf[ks] = *(const bf16x8*)(Qb + (size_t)(b * S_ + q0 + w * 16 + m) * 64
                                     + ks * 32 + quad * 8);
    // drain Q loads so vmcnt bookkeeping below is exact
    asm volatile("s_waitcnt vmcnt(0)" ::: "memory");
    __builtin_amdgcn_sched_barrier(0);

    f32x4 acc_o[4] = {};
    float Lp[4] = {};

    const ushort* kbase = Kb + (size_t)b * S_ * 64;
    const ushort* vbase = Vt + (size_t)b * 64 * S_;

    // stage one 64-j tile (2 DMA ops/wave: 1 K + 1 V; 8 waves cover 8KB each)
    auto stage = [&](int jt, int buf) {
        const int slot = w * 64 + lane;          // 0..511
        const int j = slot >> 3, cc = slot & 7;
        __builtin_amdgcn_global_load_lds(
            GPTR(kbase + (size_t)(jt * 64 + j) * 64 + ((cc ^ (j & 7)) * 8)),
            LPTR(&Ks[buf][slot * 8]), 16, 0, 0);
        __builtin_amdgcn_global_load_lds(
            GPTR(vbase + (size_t)j * S_ + jt * 64 + ((cc ^ (j & 7)) * 8)),
            LPTR(&Vs[buf][slot * 8]), 16, 0, 0);
    };

    stage(jc * 16 + 0, 0);
    stage(jc * 16 + 1, 1);

    for (int it = 0; it < 16; ++it) {
        // drain THIS tile's 2 DMAs; next tile's 2 stay in flight (counted)
        if (it < 15) asm volatile("s_waitcnt vmcnt(2)" ::: "memory");
        else         asm volatile("s_waitcnt vmcnt(0)" ::: "memory");
        __builtin_amdgcn_sched_barrier(0);
        __builtin_amdgcn_s_barrier();          // all waves' DMAs landed
        __builtin_amdgcn_sched_barrier(0);

        const ushort* ksb = Ks[it & 1];
        const ushort* vsb = Vs[it & 1];

        // S2 = (Q * 0.125*log2e) K^T
        f32x4 acc_s[4] = {};
        #pragma unroll
        for (int ks = 0; ks < 2; ++ks)
            #pragma unroll
            for (int jt4 = 0; jt4 < 4; ++jt4) {
                const int j = jt4 * 16 + m;
                const bf16x8 kf = *(const bf16x8*)&ksb[j * 64 + (((ks * 4 + quad) ^ (j & 7)) * 8)];
                acc_s[jt4] = __builtin_amdgcn_mfma_f32_16x16x32_bf16(
                    qf[ks], kf, acc_s[jt4], 0, 0, 0);
            }

        // P = exp2(S2); L += rowsum; P -> per-wave LDS stripe (bf16)
        #pragma unroll
        for (int jt4 = 0; jt4 < 4; ++jt4)
            #pragma unroll
            for (int r = 0; r < 4; ++r) {
                const float e = exp2f(acc_s[jt4][r]);
                Lp[r] += e;
                Pt[(w * 16 + quad * 4 + r) * 72 + jt4 * 16 + m] = f2bf(e);
            }

        // O += P V (same-wave LDS RAW, ordered by lgkmcnt)
        #pragma unroll
        for (int jc2 = 0; jc2 < 2; ++jc2) {
            const bf16x8 pf = *(const bf16x8*)&Pt[(w * 16 + m) * 72 + jc2 * 32 + quad * 8];
            #pragma unroll
            for (int dt = 0; dt < 4; ++dt) {
                const int d = dt * 16 + m;
                const bf16x8 vf = *(const bf16x8*)&vsb[d * 64 + (((jc2 * 4 + quad) ^ (d & 7)) * 8)];
                acc_o[dt] = __builtin_amdgcn_mfma_f32_16x16x32_bf16(pf, vf, acc_o[dt], 0, 0, 0);
            }
        }

        __builtin_amdgcn_sched_barrier(0);
        __builtin_amdgcn_s_barrier();          // all waves done reading buf
        __builtin_amdgcn_sched_barrier(0);
        if (it + 2 < 16) stage(jc * 16 + it + 2, it & 1);
    }

    #pragma unroll
    for (int r = 0; r < 4; ++r) {
        float s = Lp[r];
        #pragma unroll
        for (int off = 1; off < 16; off <<= 1)
            s += __shfl_xor(s, off, 64);
        Lp[r] = s;
    }

    // ---- write partials (unchanged layout) ----
    const size_t bj = (size_t)(b * 4 + jc);
    float* Ob = Opart + (bj << 18);
    #pragma unroll
    for (int dt = 0; dt < 4; ++dt)
        #pragma unroll
        for (int r = 0; r < 4; ++r) {
            const int row = q0 + w * 16 + quad * 4 + r;
            Ob[(size_t)row * 64 + dt * 16 + m] = acc_o[dt][r];
        }
    if (m == 0) {
        #pragma unroll
        for (int r = 0; r < 4; ++r)
            Lpart[bj * 4096 + q0 + w * 16 + quad * 4 + r] = Lp[r];
    }

    // ---- last-block-done combine (replaces the reduce kernel) ----
    __threadfence();                       // partials visible device-wide
    __syncthreads();                       // all waves' stores + fences done
    if (tid == 0) sOld = atomicAdd(&cnt[b * 32 + qt], 1);
    __syncthreads();
    if (sOld == 3) {
        __threadfence();                   // acquire: see other blocks' partials
        float* Of = out + ((size_t)b * S_ + q0) * DH;
        for (int i = tid; i < 128 * 16; i += 512) {
            const int r    = i >> 4;       // row in region, 0..127
            const int col4 = (i & 15) * 4; // 0,4,...,60
            float4 o = make_float4(0.f, 0.f, 0.f, 0.f);
            float  l = 0.f;
            #pragma unroll
            for (int jcc = 0; jcc < 4; ++jcc) {
                const float4 p = *(const float4*)(
                    Opart + (((size_t)(b * 4 + jcc)) << 18) + (size_t)(q0 + r) * 64 + col4);
                o.x += p.x; o.y += p.y; o.z += p.z; o.w += p.w;
                l += Lpart[(size_t)(b * 4 + jcc) * 4096 + q0 + r];
            }
            const float inv = 1.0f / l;
            o.x *= inv; o.y *= inv; o.z *= inv; o.w *= inv;
            *(float4*)(Of + (size_t)r * 64 + col4) = o;
        }
        if (tid == 0) cnt[b * 32 + qt] = 0;   // self-reset for next iteration
    }
}

// ---------------------------------------------------------------------------
extern "C" void kernel_launch(void* const* d_in, const int* in_sizes, int n_in,
                              void* d_out, int out_size, void* d_ws, size_t ws_size,
                              hipStream_t stream)
{
    const float* query = (const float*)d_in[0];
    const float* key_  = (const float*)d_in[1];
    const float* value = (const float*)d_in[2];
    const float* Wq    = (const float*)d_in[3];
    const float* bq    = (const float*)d_in[4];
    const float* Wk    = (const float*)d_in[5];
    const float* bk    = (const float*)d_in[6];
    const float* Wv    = (const float*)d_in[7];
    const float* bv    = (const float*)d_in[8];
    float* out = (float*)d_out;

    // ws: Qb 2MB | Kb 2MB | Vt 2MB | Opart 16MB | Lpart 256KB | cnt 512B
    // Wt_g (384KB) ALIASES Opart: consumed by proj before attn writes Opart.
    char* ws = (char*)d_ws;
    ushort* Qb    = (ushort*)(ws);
    ushort* Kb    = (ushort*)(ws + (2  << 20));
    ushort* Vt    = (ushort*)(ws + (4  << 20));
    float*  Opart = (float*) (ws + (6  << 20));
    float*  Lpart = (float*) (ws + (22 << 20));
    int*    cnt   = (int*)   (ws + (22 << 20) + (1 << 18));
    ushort* Wt_g  = (ushort*)(ws + (6  << 20));

    setup_w<<<dim3(32, 3), 256, 0, stream>>>(Wq, Wk, Wv, Wt_g, cnt);
    proj_kernel<<<dim3(1024, 3), 256, 0, stream>>>(
        query, key_, value, bq, bk, bv, Wt_g, Qb, Kb, Vt);
    attn_kernel<<<dim3(512), 512, 0, stream>>>(Qb, Kb, Vt, Opart, Lpart, cnt, out);
}

// Round 12
// 249.261 us; speedup vs baseline: 1.5847x; 1.5847x over previous
//
#include <hip/hip_runtime.h>
#include <cmath>

// B=4, S=4096, D_IN=1024, D_K=D_V=64
constexpr int B_  = 4;
constexpr int S_  = 4096;
constexpr int DIN = 1024;
constexpr int DH  = 64;

typedef short bf16x8 __attribute__((ext_vector_type(8)));
typedef float f32x4  __attribute__((ext_vector_type(4)));

#define GPTR(p) (const __attribute__((address_space(1))) unsigned int*)(p)
#define LPTR(p) (__attribute__((address_space(3))) unsigned int*)(p)

// fp32 -> bf16 RNE, raw bits
__device__ __forceinline__ ushort f2bf(float x) {
    unsigned int u = __float_as_uint(x);
    return (ushort)((u + 0x7FFFu + ((u >> 16) & 1u)) >> 16);
}

__device__ __forceinline__ bf16x8 cvt8(f32x4 a, f32x4 b) {
    union { bf16x8 v; ushort u[8]; } r;
    r.u[0] = f2bf(a[0]); r.u[1] = f2bf(a[1]); r.u[2] = f2bf(a[2]); r.u[3] = f2bf(a[3]);
    r.u[4] = f2bf(b[0]); r.u[5] = f2bf(b[1]); r.u[6] = f2bf(b[2]); r.u[7] = f2bf(b[3]);
    return r.v;
}

// softmax scale 1/8 with log2(e) folded in (softmax via exp2)
#define QSCALE 0.18033688011112042f

// ---------------------------------------------------------------------------
// setup_w: W[1024][64] fp32 -> FRAGMENT-ORDERED bf16 image.
// ---------------------------------------------------------------------------
__global__ __launch_bounds__(256) void setup_w(
    const float* __restrict__ Wq, const float* __restrict__ Wk,
    const float* __restrict__ Wv, ushort* __restrict__ Wt_g)
{
    const int y = blockIdx.y;
    const float* W = (y == 0) ? Wq : (y == 1) ? Wk : Wv;
    const int g    = blockIdx.x * 256 + threadIdx.x;
    const int lane = g & 63;
    const int nt   = (g >> 6) & 3;
    const int ks   = (g >> 8) & 1;
    const int it   = g >> 9;
    const int m    = lane & 15;
    const int quad = lane >> 4;
    const int n    = nt * 16 + m;
    const int k0   = it * 64 + (ks * 4 + quad) * 8;
    union { uint4 q; ushort u[8]; } r;
    #pragma unroll
    for (int i = 0; i < 8; ++i) r.u[i] = f2bf(W[(size_t)(k0 + i) * DH + n]);
    *(uint4*)(Wt_g + ((size_t)y << 16) + (size_t)g * 8) = r.q;
}

// ---------------------------------------------------------------------------
// Projection v5 (FROZEN at its ~74-82us floor — six schedules r0-r5 all land
// there regardless of structure. Input-read service-rate cap. Do not touch.)
// ---------------------------------------------------------------------------
__global__ __launch_bounds__(256, 4) void proj_kernel(
    const float* __restrict__ Xq, const float* __restrict__ Xk, const float* __restrict__ Xv,
    const float* __restrict__ bq, const float* __restrict__ bk, const float* __restrict__ bv,
    const ushort* __restrict__ Wt_g,
    ushort* __restrict__ Qb, ushort* __restrict__ Kb, ushort* __restrict__ Vt)
{
    __shared__ __align__(16) ushort xlds[16384];   // 32KB

    const int y = blockIdx.y;
    const float *X, *bias;
    if (y == 0)      { X = Xq; bias = bq; }
    else if (y == 1) { X = Xk; bias = bk; }
    else             { X = Xv; bias = bv; }

    const int tid  = threadIdx.x;
    const int w    = tid >> 6;
    const int lane = tid & 63;
    const int m    = lane & 15;
    const int quad = lane >> 4;
    const int row0 = blockIdx.x * 16;

    {
        f32x4 va[8], vb[8];
        #pragma unroll
        for (int r = 0; r < 4; ++r) {
            const float* src = X + (size_t)(row0 + w * 4 + r) * DIN + lane * 8;
            #pragma unroll
            for (int sg = 0; sg < 2; ++sg) {
                va[r * 2 + sg] = *(const f32x4*)(src + sg * 512);
                vb[r * 2 + sg] = *(const f32x4*)(src + sg * 512 + 4);
            }
        }
        __builtin_amdgcn_sched_barrier(0);
        #pragma unroll
        for (int r = 0; r < 4; ++r) {
            const int row = w * 4 + r;
            #pragma unroll
            for (int sg = 0; sg < 2; ++sg) {
                const int wi = sg * 8 + (lane >> 3);
                const int fx = (lane & 7) ^ (row & 7);
                *(bf16x8*)&xlds[((wi * 16 + row) * 8 + fx) * 8] =
                    cvt8(va[r * 2 + sg], vb[r * 2 + sg]);
            }
        }
    }
    __syncthreads();

    const float bias_v = bias[w * 16 + m];
    const ushort* wbase = Wt_g + ((size_t)y << 16) + (size_t)(w * 64 + lane) * 8;

    f32x4 acc = {};
    bf16x8 wf0 = *(const bf16x8*)(wbase);
    bf16x8 wf1 = *(const bf16x8*)(wbase + 2048);
    #pragma unroll
    for (int wi = 0; wi < 16; ++wi) {
        bf16x8 nf0 = wf0, nf1 = wf1;
        if (wi < 15) {
            nf0 = *(const bf16x8*)(wbase + (size_t)(wi + 1) * 4096);
            nf1 = *(const bf16x8*)(wbase + (size_t)(wi + 1) * 4096 + 2048);
        }
        const bf16x8 a0 = *(const bf16x8*)&xlds[((wi * 16 + m) * 8 + ( quad      ^ (m & 7))) * 8];
        const bf16x8 a1 = *(const bf16x8*)&xlds[((wi * 16 + m) * 8 + ((4 + quad) ^ (m & 7))) * 8];
        acc = __builtin_amdgcn_mfma_f32_16x16x32_bf16(a0, wf0, acc, 0, 0, 0);
        acc = __builtin_amdgcn_mfma_f32_16x16x32_bf16(a1, wf1, acc, 0, 0, 0);
        wf0 = nf0; wf1 = nf1;
    }

    if (y < 2) {
        ushort* Out = (y == 0) ? Qb : Kb;
        const float sc = (y == 0) ? QSCALE : 1.0f;
        #pragma unroll
        for (int j = 0; j < 4; ++j) {
            const int row = row0 + quad * 4 + j;
            Out[(size_t)row * DH + w * 16 + m] = f2bf((acc[j] + bias_v) * sc);
        }
    } else {
        __syncthreads();
        ushort (*Vx)[32] = (ushort(*)[32])xlds;
        #pragma unroll
        for (int j = 0; j < 4; ++j)
            Vx[w * 16 + m][quad * 4 + j] = f2bf(acc[j] + bias_v);
        __syncthreads();
        const int batch = row0 >> 12;
        const int s0    = row0 & 4095;
        if (tid < 128) {
            const int d = tid >> 1, h = tid & 1;
            const uint4 v = *(const uint4*)&Vx[d][h * 8];
            *(uint4*)(Vt + ((size_t)batch * 64 + d) * S_ + s0 + h * 8) = v;
        }
    }
}

// ---------------------------------------------------------------------------
// Flash attention v4 (r8, PROVEN BEST — restored verbatim). BQ=128, 512-thr
// blocks, 8 waves of 16 q-rows sharing one K/V stream; XCD remap pins each
// (b,jc) K/V chunk to one XCD's L2 (2 chunks = 2MB per XCD, fits 4MB);
// counted-vmcnt double-buffer costs no occupancy (2 blk/CU, 16 waves/CU).
// r9 post-mortem: do NOT fuse the combine — per-block __threadfence (XCD
// coherence flush) cost ~125us, vs the ~9us reduce dispatch it saved.
// ---------------------------------------------------------------------------
__global__ __launch_bounds__(512, 4) void attn_kernel(
    const ushort* __restrict__ Qb, const ushort* __restrict__ Kb,
    const ushort* __restrict__ Vt, float* __restrict__ Opart, float* __restrict__ Lpart)
{
    __shared__ ushort Ks[2][4096];   // [buf][j][d], chunk-XOR swizzled (8KB)
    __shared__ ushort Vs[2][4096];   // [buf][d][j], chunk-XOR swizzled (8KB)
    __shared__ ushort Pt[128 * 72];  // per-wave stripes (8 waves), padded

    const int tid  = threadIdx.x;
    const int w    = tid >> 6;          // 0..7: q-rows [w*16, w*16+16)
    const int lane = tid & 63;
    const int m    = lane & 15;
    const int quad = lane >> 4;

    // XCD-locality remap: chunk c=(b,jc) pinned to XCD u&7 (2 chunks/XCD)
    const int u  = blockIdx.x;          // 0..511
    const int c  = (u & 7) * 2 + ((u >> 3) >> 5);
    const int qt = (u >> 3) & 31;
    const int b  = c >> 2, jc = c & 3;
    const int q0 = qt * 128;

    bf16x8 qf[2];
    #pragma unroll
    for (int ks = 0; ks < 2; ++ks)
        qf[ks] = *(const bf16x8*)(Qb + (size_t)(b * S_ + q0 + w * 16 + m) * 64
                                     + ks * 32 + quad * 8);
    // drain Q loads so vmcnt bookkeeping below is exact
    asm volatile("s_waitcnt vmcnt(0)" ::: "memory");
    __builtin_amdgcn_sched_barrier(0);

    f32x4 acc_o[4] = {};
    float Lp[4] = {};

    const ushort* kbase = Kb + (size_t)b * S_ * 64;
    const ushort* vbase = Vt + (size_t)b * 64 * S_;

    // stage one 64-j tile (2 DMA ops/wave: 1 K + 1 V; 8 waves cover 8KB each)
    auto stage = [&](int jt, int buf) {
        const int slot = w * 64 + lane;          // 0..511
        const int j = slot >> 3, cc = slot & 7;
        __builtin_amdgcn_global_load_lds(
            GPTR(kbase + (size_t)(jt * 64 + j) * 64 + ((cc ^ (j & 7)) * 8)),
            LPTR(&Ks[buf][slot * 8]), 16, 0, 0);
        __builtin_amdgcn_global_load_lds(
            GPTR(vbase + (size_t)j * S_ + jt * 64 + ((cc ^ (j & 7)) * 8)),
            LPTR(&Vs[buf][slot * 8]), 16, 0, 0);
    };

    stage(jc * 16 + 0, 0);
    stage(jc * 16 + 1, 1);

    for (int it = 0; it < 16; ++it) {
        // drain THIS tile's 2 DMAs; next tile's 2 stay in flight (counted)
        if (it < 15) asm volatile("s_waitcnt vmcnt(2)" ::: "memory");
        else         asm volatile("s_waitcnt vmcnt(0)" ::: "memory");
        __builtin_amdgcn_sched_barrier(0);
        __builtin_amdgcn_s_barrier();          // all waves' DMAs landed
        __builtin_amdgcn_sched_barrier(0);

        const ushort* ksb = Ks[it & 1];
        const ushort* vsb = Vs[it & 1];

        // S2 = (Q * 0.125*log2e) K^T
        f32x4 acc_s[4] = {};
        #pragma unroll
        for (int ks = 0; ks < 2; ++ks)
            #pragma unroll
            for (int jt4 = 0; jt4 < 4; ++jt4) {
                const int j = jt4 * 16 + m;
                const bf16x8 kf = *(const bf16x8*)&ksb[j * 64 + (((ks * 4 + quad) ^ (j & 7)) * 8)];
                acc_s[jt4] = __builtin_amdgcn_mfma_f32_16x16x32_bf16(
                    qf[ks], kf, acc_s[jt4], 0, 0, 0);
            }

        // P = exp2(S2); L += rowsum; P -> per-wave LDS stripe (bf16)
        #pragma unroll
        for (int jt4 = 0; jt4 < 4; ++jt4)
            #pragma unroll
            for (int r = 0; r < 4; ++r) {
                const float e = exp2f(acc_s[jt4][r]);
                Lp[r] += e;
                Pt[(w * 16 + quad * 4 + r) * 72 + jt4 * 16 + m] = f2bf(e);
            }

        // O += P V (same-wave LDS RAW, ordered by lgkmcnt)
        #pragma unroll
        for (int jc2 = 0; jc2 < 2; ++jc2) {
            const bf16x8 pf = *(const bf16x8*)&Pt[(w * 16 + m) * 72 + jc2 * 32 + quad * 8];
            #pragma unroll
            for (int dt = 0; dt < 4; ++dt) {
                const int d = dt * 16 + m;
                const bf16x8 vf = *(const bf16x8*)&vsb[d * 64 + (((jc2 * 4 + quad) ^ (d & 7)) * 8)];
                acc_o[dt] = __builtin_amdgcn_mfma_f32_16x16x32_bf16(pf, vf, acc_o[dt], 0, 0, 0);
            }
        }

        __builtin_amdgcn_sched_barrier(0);
        __builtin_amdgcn_s_barrier();          // all waves done reading buf
        __builtin_amdgcn_sched_barrier(0);
        if (it + 2 < 16) stage(jc * 16 + it + 2, it & 1);
    }

    #pragma unroll
    for (int r = 0; r < 4; ++r) {
        float s = Lp[r];
        #pragma unroll
        for (int off = 1; off < 16; off <<= 1)
            s += __shfl_xor(s, off, 64);
        Lp[r] = s;
    }

    const size_t bj = (size_t)(b * 4 + jc);
    float* Ob = Opart + (bj << 18);
    #pragma unroll
    for (int dt = 0; dt < 4; ++dt)
        #pragma unroll
        for (int r = 0; r < 4; ++r) {
            const int row = q0 + w * 16 + quad * 4 + r;
            Ob[(size_t)row * 64 + dt * 16 + m] = acc_o[dt][r];
        }
    if (m == 0) {
        #pragma unroll
        for (int r = 0; r < 4; ++r)
            Lpart[bj * 4096 + q0 + w * 16 + quad * 4 + r] = Lp[r];
    }
}

// ---------------------------------------------------------------------------
// Combine j-chunk partials: out = (sum_jc O) / (sum_jc L)
// ---------------------------------------------------------------------------
__global__ __launch_bounds__(256) void reduce_kernel(
    const float* __restrict__ Opart, const float* __restrict__ Lpart, float* __restrict__ out)
{
    const int g    = blockIdx.x * 256 + threadIdx.x;
    const int base = g << 2;
    const int b    = base >> 18;
    const int rem  = base & 0x3FFFF;
    const int q    = rem >> 6;
    float4 o = make_float4(0.f, 0.f, 0.f, 0.f);
    float  l = 0.f;
    #pragma unroll
    for (int jcc = 0; jcc < 4; ++jcc) {
        const float4 p = *(const float4*)(Opart + (((size_t)(b * 4 + jcc)) << 18) + rem);
        o.x += p.x; o.y += p.y; o.z += p.z; o.w += p.w;
        l += Lpart[(size_t)(b * 4 + jcc) * 4096 + q];
    }
    const float inv = 1.0f / l;
    o.x *= inv; o.y *= inv; o.z *= inv; o.w *= inv;
    *(float4*)(out + base) = o;
}

// ---------------------------------------------------------------------------
extern "C" void kernel_launch(void* const* d_in, const int* in_sizes, int n_in,
                              void* d_out, int out_size, void* d_ws, size_t ws_size,
                              hipStream_t stream)
{
    const float* query = (const float*)d_in[0];
    const float* key_  = (const float*)d_in[1];
    const float* value = (const float*)d_in[2];
    const float* Wq    = (const float*)d_in[3];
    const float* bq    = (const float*)d_in[4];
    const float* Wk    = (const float*)d_in[5];
    const float* bk    = (const float*)d_in[6];
    const float* Wv    = (const float*)d_in[7];
    const float* bv    = (const float*)d_in[8];
    float* out = (float*)d_out;

    // ws: Qb 2MB | Kb 2MB | Vt 2MB | Opart 16MB | Lpart 256KB  (22.25MB)
    // Wt_g (384KB) ALIASES Opart: consumed by proj before attn writes Opart.
    char* ws = (char*)d_ws;
    ushort* Qb    = (ushort*)(ws);
    ushort* Kb    = (ushort*)(ws + (2  << 20));
    ushort* Vt    = (ushort*)(ws + (4  << 20));
    float*  Opart = (float*) (ws + (6  << 20));
    float*  Lpart = (float*) (ws + (22 << 20));
    ushort* Wt_g  = (ushort*)(ws + (6  << 20));

    setup_w<<<dim3(32, 3), 256, 0, stream>>>(Wq, Wk, Wv, Wt_g);
    proj_kernel<<<dim3(1024, 3), 256, 0, stream>>>(
        query, key_, value, bq, bk, bv, Wt_g, Qb, Kb, Vt);
    attn_kernel<<<dim3(512), 512, 0, stream>>>(Qb, Kb, Vt, Opart, Lpart);
    reduce_kernel<<<dim3(1024), 256, 0, stream>>>(Opart, Lpart, out);
}